// Round 1
// baseline (2175.687 us; speedup 1.0000x reference)
//
#include <hip/hip_runtime.h>
#include <hip/hip_bf16.h>
#include <stdint.h>
#include <stddef.h>

#define LAYERS 8
#define NCH 256
#define NMEL 640
#define NBATCH 16
#define SEQT 4096
#define BTROWS (NBATCH * SEQT)   // 65536
#define PADT 128
#define TPAD (SEQT + 2 * PADT)   // 4352
#define KX 1408                  // 3*256 + 640

typedef __hip_bfloat16 bf16;
typedef __attribute__((ext_vector_type(8))) short short8;
typedef __attribute__((ext_vector_type(4))) float f32x4;

__device__ __forceinline__ void g2l16(const void* g, void* l) {
  __builtin_amdgcn_global_load_lds(
      (const __attribute__((address_space(1))) unsigned int*)g,
      (__attribute__((address_space(3))) unsigned int*)l, 16, 0, 0);
}

__device__ __forceinline__ float fsigmoid(float x) { return 1.f / (1.f + __expf(-x)); }
__device__ __forceinline__ float ftanh_(float x) { return 1.f - 2.f / (__expf(2.f * x) + 1.f); }

// ---------------------------------------------------------------------------
// GEMM1: x = [h(t-d); h(t); h(t+d); spect] @ Wstack^T ; acts = tanh(x1)*sig(x2)
// Block: 128 rows x (128 tanh cols + 128 matching sigmoid cols). 4 waves 2x2.
// ---------------------------------------------------------------------------
__global__ __launch_bounds__(256, 2) void gemm1_kernel(
    const bf16* __restrict__ hpad, const bf16* __restrict__ spect,
    const bf16* __restrict__ wx,   // [512][1408] this layer, n-major
    const float* __restrict__ xb,  // [512] combined in_b + cond_b
    bf16* __restrict__ acts, int dil)
{
  __shared__ alignas(16) short lds[3 * 4096];
  short* sA  = lds;
  short* sB1 = lds + 4096;
  short* sB2 = lds + 8192;

  const int tid  = threadIdx.x;
  const int lane = tid & 63;
  const int wid  = tid >> 6;
  const int wm   = wid >> 1;
  const int wn   = wid & 1;

  const int m0 = blockIdx.x * 128;
  const int c0 = blockIdx.y * 128;     // 0 or 128 (tanh channel tile)
  const int b  = m0 >> 12;             // tile fully inside one batch
  const int t0 = m0 & (SEQT - 1);

  const f32x4 fzero = {0.f, 0.f, 0.f, 0.f};
  f32x4 acc1[4][4], acc2[4][4];
#pragma unroll
  for (int i = 0; i < 4; ++i)
#pragma unroll
    for (int j = 0; j < 4; ++j) { acc1[i][j] = fzero; acc2[i][j] = fzero; }

  const int r0  = tid & 127;
  const int kc0 = tid >> 7;            // 0 or 1 (second chunk is kc0+2)

  const bf16* hrow = hpad + ((size_t)(b * TPAD + PADT + t0 + r0)) * NCH + kc0 * 8;
  const bf16* srow = spect + (size_t)(m0 + r0) * NMEL + kc0 * 8;
  const bf16* pB1  = wx + (size_t)(c0 + r0) * KX + kc0 * 8;
  const bf16* pB2  = pB1 + (size_t)256 * KX;

  short* dA0  = sA  + tid * 8;
  short* dA1  = sA  + (tid + 256) * 8;
  short* dB10 = sB1 + tid * 8;
  short* dB11 = sB1 + (tid + 256) * 8;
  short* dB20 = sB2 + tid * 8;
  short* dB21 = sB2 + (tid + 256) * 8;

  for (int kt = 0; kt < 44; ++kt) {
    const bf16* a0;
    if (kt < 24) {                      // conv taps: k-seg [0,768)
      const int tap = kt >> 3;          // 0,1,2
      const int ch  = (kt & 7) << 5;    // channel block
      a0 = hrow + (ptrdiff_t)(tap - 1) * dil * NCH + ch;
    } else {                            // spect: k-seg [768,1408)
      a0 = srow + ((kt - 24) << 5);
    }
    const bf16* w1 = pB1 + kt * 32;
    const bf16* w2 = pB2 + kt * 32;
    g2l16(a0,      dA0);
    g2l16(a0 + 16, dA1);
    g2l16(w1,      dB10);
    g2l16(w1 + 16, dB11);
    g2l16(w2,      dB20);
    g2l16(w2 + 16, dB21);
    __syncthreads();

    const int rl = lane & 15;
    const int kc = lane >> 4;
    short8 af[4], bfa[4], bfb[4];
#pragma unroll
    for (int f = 0; f < 4; ++f) {
      const int rowA = kc * 128 + wm * 64 + f * 16 + rl;
      const int rowB = kc * 128 + wn * 64 + f * 16 + rl;
      af[f]  = *(const short8*)(sA  + rowA * 8);
      bfa[f] = *(const short8*)(sB1 + rowB * 8);
      bfb[f] = *(const short8*)(sB2 + rowB * 8);
    }
#pragma unroll
    for (int i = 0; i < 4; ++i)
#pragma unroll
      for (int j = 0; j < 4; ++j) {
        acc1[i][j] = __builtin_amdgcn_mfma_f32_16x16x32_bf16(af[i], bfa[j], acc1[i][j], 0, 0, 0);
        acc2[i][j] = __builtin_amdgcn_mfma_f32_16x16x32_bf16(af[i], bfb[j], acc2[i][j], 0, 0, 0);
      }
    __syncthreads();
  }

  const int rl2 = lane & 15;
  const int ro  = (lane >> 4) * 4;
#pragma unroll
  for (int i = 0; i < 4; ++i) {
#pragma unroll
    for (int j = 0; j < 4; ++j) {
      const int col = c0 + wn * 64 + j * 16 + rl2;   // tanh channel, [0,256)
      const float bx1 = xb[col];
      const float bx2 = xb[col + 256];
#pragma unroll
      for (int r = 0; r < 4; ++r) {
        const int m = m0 + wm * 64 + i * 16 + ro + r;
        const float x1 = acc1[i][j][r] + bx1;
        const float x2 = acc2[i][j][r] + bx2;
        acts[(size_t)m * NCH + col] = __float2bfloat16(ftanh_(x1) * fsigmoid(x2));
      }
    }
  }
}

// ---------------------------------------------------------------------------
// GEMM2: rs = acts @ Wr^T (+rb); n<256 -> h += rs ; n>=256 -> skip (+)= rs
// ---------------------------------------------------------------------------
__global__ __launch_bounds__(256, 2) void gemm2_kernel(
    const bf16* __restrict__ acts, const bf16* __restrict__ wr,  // [512][256]
    const float* __restrict__ rb, bf16* __restrict__ hpad,
    float* __restrict__ skip, const int first)
{
  __shared__ alignas(16) short lds[2 * 4096];
  short* sA = lds;
  short* sB = lds + 4096;

  const int tid  = threadIdx.x;
  const int lane = tid & 63;
  const int wid  = tid >> 6;
  const int wm   = wid >> 1;
  const int wn   = wid & 1;

  const int m0 = blockIdx.x * 128;
  const int n0 = blockIdx.y * 128;     // 0,128,256,384
  const int b  = m0 >> 12;

  const f32x4 fzero = {0.f, 0.f, 0.f, 0.f};
  f32x4 acc[4][4];
#pragma unroll
  for (int i = 0; i < 4; ++i)
#pragma unroll
    for (int j = 0; j < 4; ++j) acc[i][j] = fzero;

  const int r0  = tid & 127;
  const int kc0 = tid >> 7;
  const bf16* pA = acts + (size_t)(m0 + r0) * NCH + kc0 * 8;
  const bf16* pB = wr + (size_t)(n0 + r0) * NCH + kc0 * 8;

  for (int kt = 0; kt < 8; ++kt) {
    g2l16(pA + kt * 32,      sA + tid * 8);
    g2l16(pA + kt * 32 + 16, sA + (tid + 256) * 8);
    g2l16(pB + kt * 32,      sB + tid * 8);
    g2l16(pB + kt * 32 + 16, sB + (tid + 256) * 8);
    __syncthreads();

    const int rl = lane & 15;
    const int kc = lane >> 4;
    short8 af[4], bfr[4];
#pragma unroll
    for (int f = 0; f < 4; ++f) {
      af[f]  = *(const short8*)(sA + (kc * 128 + wm * 64 + f * 16 + rl) * 8);
      bfr[f] = *(const short8*)(sB + (kc * 128 + wn * 64 + f * 16 + rl) * 8);
    }
#pragma unroll
    for (int i = 0; i < 4; ++i)
#pragma unroll
      for (int j = 0; j < 4; ++j)
        acc[i][j] = __builtin_amdgcn_mfma_f32_16x16x32_bf16(af[i], bfr[j], acc[i][j], 0, 0, 0);
    __syncthreads();
  }

  const int rl2 = lane & 15;
  const int ro  = (lane >> 4) * 4;
#pragma unroll
  for (int i = 0; i < 4; ++i) {
#pragma unroll
    for (int j = 0; j < 4; ++j) {
      const int n = n0 + wn * 64 + j * 16 + rl2;
      const float bias = rb[n];
#pragma unroll
      for (int r = 0; r < 4; ++r) {
        const int m = m0 + wm * 64 + i * 16 + ro + r;
        const float v = acc[i][j][r] + bias;
        if (n < NCH) {
          const size_t hi = ((size_t)(b * TPAD + PADT + (m & (SEQT - 1)))) * NCH + n;
          hpad[hi] = __float2bfloat16(__bfloat162float(hpad[hi]) + v);
        } else {
          const size_t si = (size_t)m * NCH + (n - NCH);
          if (first) skip[si] = v;
          else       skip[si] += v;
        }
      }
    }
  }
}

// ---------------------------------------------------------------------------
// aux kernels
// ---------------------------------------------------------------------------
__global__ void start_kernel(const float* __restrict__ audio, const float* __restrict__ sw,
                             const float* __restrict__ sb, bf16* __restrict__ hpad)
{
  const int idx = blockIdx.x * 256 + threadIdx.x;   // < 16777216
  const int m = idx >> 8;
  const int c = idx & 255;
  const int b = m >> 12;
  const int t = m & (SEQT - 1);
  const float* a = audio + (size_t)m * 4;
  float v = sb[c] + a[0] * sw[c] + a[1] * sw[256 + c] + a[2] * sw[512 + c] + a[3] * sw[768 + c];
  hpad[((size_t)(b * TPAD + PADT + t)) * NCH + c] = __float2bfloat16(v);
}

__global__ void cvt_spect_kernel(const float* __restrict__ s, bf16* __restrict__ d)
{
  const size_t i = ((size_t)blockIdx.x * 256 + threadIdx.x) * 4;
  const float4 v = *(const float4*)(s + i);
  bf16* o = d + i;
  o[0] = __float2bfloat16(v.x);
  o[1] = __float2bfloat16(v.y);
  o[2] = __float2bfloat16(v.z);
  o[3] = __float2bfloat16(v.w);
}

__global__ void prep_wx_kernel(const float* __restrict__ in_w, const float* __restrict__ cond_w,
                               bf16* __restrict__ wx)
{
  const size_t idx = (size_t)blockIdx.x * 256 + threadIdx.x;
  if (idx >= (size_t)LAYERS * 512 * KX) return;
  const int k = (int)(idx % KX);
  const int n = (int)((idx / KX) & 511);
  const int i = (int)(idx / ((size_t)512 * KX));
  float v;
  if (k < 768) {
    const int tap = k >> 8;
    const int c   = k & 255;
    v = in_w[(size_t)(((i * 3 + tap) << 8) + c) * 512 + n];
  } else {
    v = cond_w[(size_t)(i * NMEL + (k - 768)) * 512 + n];
  }
  wx[idx] = __float2bfloat16(v);
}

__global__ void prep_wr_kernel(const float* __restrict__ rs_w, const float* __restrict__ rs_w_last,
                               bf16* __restrict__ wr)
{
  const int idx = blockIdx.x * 256 + threadIdx.x;   // < 1048576
  const int k = idx & 255;
  const int n = (idx >> 8) & 511;
  const int i = idx >> 17;
  float v;
  if (i < LAYERS - 1) v = rs_w[(size_t)((i << 8) + k) * 512 + n];
  else                v = (n >= 256) ? rs_w_last[(k << 8) + (n - 256)] : 0.f;
  wr[idx] = __float2bfloat16(v);
}

__global__ void prep_bias_kernel(const float* __restrict__ in_b, const float* __restrict__ cond_b,
                                 const float* __restrict__ rs_b, const float* __restrict__ rs_b_last,
                                 float* __restrict__ xb, float* __restrict__ rb)
{
  const int idx = blockIdx.x * 256 + threadIdx.x;   // < 4096
  if (idx >= LAYERS * 512) return;
  const int i = idx >> 9;
  const int n = idx & 511;
  xb[idx] = in_b[idx] + cond_b[idx];
  rb[idx] = (i < LAYERS - 1) ? rs_b[idx] : ((n >= 256) ? rs_b_last[n - 256] : 0.f);
}

__global__ void end_kernel(const float* __restrict__ skip, const float* __restrict__ ew,
                           const float* __restrict__ eb, float* __restrict__ out)
{
  const int idx = blockIdx.x * 256 + threadIdx.x;   // < 524288
  const int m = idx >> 3;
  const int j = idx & 7;
  const float* srow = skip + (size_t)m * NCH;
  float s = eb[j];
#pragma unroll 4
  for (int c = 0; c < NCH; ++c) s += srow[c] * ew[c * 8 + j];
  out[idx] = s;
}

// ---------------------------------------------------------------------------
extern "C" void kernel_launch(void* const* d_in, const int* in_sizes, int n_in,
                              void* d_out, int out_size, void* d_ws, size_t ws_size,
                              hipStream_t stream)
{
  const float* audio     = (const float*)d_in[0];
  const float* spect     = (const float*)d_in[1];
  const float* start_w   = (const float*)d_in[2];
  const float* start_b   = (const float*)d_in[3];
  const float* in_w      = (const float*)d_in[4];
  const float* in_b      = (const float*)d_in[5];
  const float* cond_w    = (const float*)d_in[6];
  const float* cond_b    = (const float*)d_in[7];
  const float* rs_w      = (const float*)d_in[8];
  const float* rs_b      = (const float*)d_in[9];
  const float* rs_w_last = (const float*)d_in[10];
  const float* rs_b_last = (const float*)d_in[11];
  const float* end_w     = (const float*)d_in[12];
  const float* end_b     = (const float*)d_in[13];
  float* out = (float*)d_out;

  char* p = (char*)d_ws;
  bf16* spect_bf = (bf16*)p;  p += (size_t)BTROWS * NMEL * 2;          // 83.9 MB
  bf16* hpad     = (bf16*)p;  p += (size_t)NBATCH * TPAD * NCH * 2;    // 35.7 MB
  bf16* actsb    = (bf16*)p;  p += (size_t)BTROWS * NCH * 2;           // 33.6 MB
  float* skip    = (float*)p; p += (size_t)BTROWS * NCH * 4;           // 67.1 MB
  bf16* wx       = (bf16*)p;  p += (size_t)LAYERS * 512 * KX * 2;      // 11.5 MB
  bf16* wr       = (bf16*)p;  p += (size_t)LAYERS * 512 * 256 * 2;     //  2.1 MB
  float* xb      = (float*)p; p += (size_t)LAYERS * 512 * 4;
  float* rb      = (float*)p; p += (size_t)LAYERS * 512 * 4;
  if ((size_t)(p - (char*)d_ws) > ws_size) return;  // insufficient workspace

  hipMemsetAsync(hpad, 0, (size_t)NBATCH * TPAD * NCH * 2, stream);
  prep_wx_kernel<<<(LAYERS * 512 * KX + 255) / 256, 256, 0, stream>>>(in_w, cond_w, wx);
  prep_wr_kernel<<<(LAYERS * 512 * 256) / 256, 256, 0, stream>>>(rs_w, rs_w_last, wr);
  prep_bias_kernel<<<16, 256, 0, stream>>>(in_b, cond_b, rs_b, rs_b_last, xb, rb);
  cvt_spect_kernel<<<(BTROWS * NMEL / 4) / 256, 256, 0, stream>>>(spect, spect_bf);
  start_kernel<<<(BTROWS * NCH) / 256, 256, 0, stream>>>(audio, start_w, start_b, hpad);

  for (int i = 0; i < LAYERS; ++i) {
    gemm1_kernel<<<dim3(512, 2), 256, 0, stream>>>(hpad, spect_bf, wx + (size_t)i * 512 * KX,
                                                   xb + i * 512, actsb, 1 << i);
    gemm2_kernel<<<dim3(512, 4), 256, 0, stream>>>(actsb, wr + (size_t)i * 512 * 256,
                                                   rb + i * 512, hpad, skip, i == 0 ? 1 : 0);
  }
  end_kernel<<<(BTROWS * 8) / 256, 256, 0, stream>>>(skip, end_w, end_b, out);
}